// Round 14
// baseline (140.213 us; speedup 1.0000x reference)
//
#include <hip/hip_runtime.h>

#define NN 50000
#define D 128
#define BLK_E 4096   // edges per block in passes A/C (256 thr x 16)

typedef short bf16x8 __attribute__((ext_vector_type(8)));
typedef float f32x16 __attribute__((ext_vector_type(16)));

__device__ __forceinline__ unsigned bf16r(float f) {   // RNE round to bf16
    unsigned u = __float_as_uint(f);
    return (u + 0x7FFFu + ((u >> 16) & 1u)) >> 16;
}
__device__ __forceinline__ float bflo(unsigned u) { return __uint_as_float(u << 16); }
__device__ __forceinline__ float bfhi(unsigned u) { return __uint_as_float(u & 0xFFFF0000u); }

// ---------------- pass A: per-block dst>>8 histogram (+ W/x bf16 converts) ----

__global__ void passA_k(const int* __restrict__ ei, int E,
                        int* __restrict__ counts, int nebl,
                        const float* __restrict__ Wl, const float* __restrict__ Wr,
                        uint* __restrict__ wb,
                        const float* __restrict__ x, uint* __restrict__ xb, int nquad) {
    int bid = blockIdx.x;
    int t = threadIdx.x;
    if (bid < nebl) {
        __shared__ int dh[256];
        dh[t] = 0;
        __syncthreads();
        const int* dst = ei + E;
        int base = bid * BLK_E + t * 16;
        if (base + 16 <= E) {
            #pragma unroll
            for (int q = 0; q < 4; ++q) {
                int4 d4 = *(const int4*)(dst + base + q * 4);
                atomicAdd(&dh[d4.x >> 8], 1);
                atomicAdd(&dh[d4.y >> 8], 1);
                atomicAdd(&dh[d4.z >> 8], 1);
                atomicAdd(&dh[d4.w >> 8], 1);
            }
        } else {
            for (int e = base; e < E; ++e) atomicAdd(&dh[dst[e] >> 8], 1);
        }
        __syncthreads();
        counts[bid * 256 + t] = dh[t];
    } else if (bid < nebl + 64) {
        int i = (bid - nebl) * 256 + t;           // 0..16383
        int nrow = i >> 7;
        int k = (i & 127) * 2;
        const float* W = (k < 128) ? Wl : Wr;
        int kk = k & 127;
        uint lo = bf16r(W[nrow * 128 + kk]);
        uint hi = bf16r(W[nrow * 128 + kk + 1]);
        wb[i] = (hi << 16) | lo;
    } else {
        int i = (bid - nebl - 64) * 256 + t;
        if (i >= nquad) return;
        float4 v = ((const float4*)x)[i];
        uint2 p;
        p.x = (bf16r(v.y) << 16) | bf16r(v.x);
        p.y = (bf16r(v.w) << 16) | bf16r(v.z);
        ((uint2*)xb)[i] = p;
    }
}

// ---------------- pass B: column-exclusive prefix + bin bases ----------------

__global__ void passB_k(int* __restrict__ counts, int nebl,
                        int* __restrict__ binBase) {
    __shared__ int sm[256];
    int t = threadIdx.x;
    int run = 0;
    for (int b = 0; b < nebl; b += 8) {
        int v[8];
        #pragma unroll
        for (int j = 0; j < 8; ++j)
            v[j] = (b + j < nebl) ? counts[(b + j) * 256 + t] : 0;
        #pragma unroll
        for (int j = 0; j < 8; ++j) {
            if (b + j < nebl) counts[(b + j) * 256 + t] = run;
            run += v[j];
        }
    }
    int v = run;                      // column total
    sm[t] = v;
    __syncthreads();
    for (int off = 1; off < 256; off <<= 1) {
        int a = (t >= off) ? sm[t - off] : 0;
        __syncthreads();
        sm[t] += a;
        __syncthreads();
    }
    binBase[t] = sm[t] - v;           // exclusive
    if (t == 255) binBase[256] = sm[255];   // == E
}

// ---------------- pass C: scatter edges into dst>>8 partitions --------------
// upack = (dst&255)<<16 | src  (src < 50000 < 2^16)

__global__ void passC_k(const int* __restrict__ ei, int E,
                        const int* __restrict__ counts,
                        const int* __restrict__ binBase,
                        uint* __restrict__ upack, int nebl) {
    __shared__ int cur[256];
    int t = threadIdx.x, bid = blockIdx.x;
    cur[t] = counts[bid * 256 + t] + binBase[t];
    __syncthreads();
    const int* dst = ei + E;
    const int* src = ei;
    int base = bid * BLK_E + t * 16;
    if (base + 16 <= E) {
        #pragma unroll
        for (int q = 0; q < 4; ++q) {
            int4 d4 = *(const int4*)(dst + base + q * 4);
            int4 s4 = *(const int4*)(src + base + q * 4);
            int p;
            p = atomicAdd(&cur[d4.x >> 8], 1);
            upack[p] = ((uint)(d4.x & 255) << 16) | (uint)s4.x;
            p = atomicAdd(&cur[d4.y >> 8], 1);
            upack[p] = ((uint)(d4.y & 255) << 16) | (uint)s4.y;
            p = atomicAdd(&cur[d4.z >> 8], 1);
            upack[p] = ((uint)(d4.z & 255) << 16) | (uint)s4.z;
            p = atomicAdd(&cur[d4.w >> 8], 1);
            upack[p] = ((uint)(d4.w & 255) << 16) | (uint)s4.w;
        }
    } else {
        for (int e = base; e < E; ++e) {
            int d = dst[e];
            int p = atomicAdd(&cur[d >> 8], 1);
            upack[p] = ((uint)(d & 255) << 16) | (uint)src[e];
        }
    }
}

// ---------------- pass D: per-partition padded-CSR build (LDS only) ---------
// Rows padded to 4-int (16B) multiples so fused reads neighbor ids as ONE
// int4/iter (R13's scalar ushort id loads cost +6us/dispatch — G13).
// padBase[p] = align4(binBase[p]) + p*768  (per-partition pad capacity
// 256 rows x 3 + base align <= 768, deterministic, no global scan).

__global__ void passD_k(const uint* __restrict__ upack,
                        const int* __restrict__ binBase,
                        int* __restrict__ rowptrA, int* __restrict__ degA,
                        int* __restrict__ csr, int N) {
    __shared__ int lh[256], sm[256], cur[256];
    int p = blockIdx.x, t = threadIdx.x;
    int s0 = binBase[p], s1 = binBase[p + 1];
    lh[t] = 0;
    __syncthreads();
    for (int e = s0 + t; e < s1; e += 256)
        atomicAdd(&lh[upack[e] >> 16], 1);
    __syncthreads();
    int dg = lh[t];
    int pd = (dg + 3) & ~3;           // padded degree
    sm[t] = pd;
    __syncthreads();
    for (int off = 1; off < 256; off <<= 1) {
        int a = (t >= off) ? sm[t - off] : 0;
        __syncthreads();
        sm[t] += a;
        __syncthreads();
    }
    int lpb = sm[t] - pd;             // exclusive padded offset in partition
    int pb  = ((s0 + 3) & ~3) + p * 768;
    int d = p * 256 + t;
    if (d < N) { rowptrA[d] = pb + lpb; degA[d] = dg; }
    cur[t] = lpb;
    __syncthreads();
    for (int e = s0 + t; e < s1; e += 256) {
        uint u = upack[e];
        int r = atomicAdd(&cur[u >> 16], 1);
        csr[pb + r] = (int)(u & 0xFFFFu);
    }
}

// ---------------- fused layer: agg(32 nodes) -> LDS -> MFMA ----------
// R6-measured-best inner loop (44us / FETCH 65MB): int ids, 4-deep gather,
// 2 groups of 16 nodes, plain launch_bounds(256). Ids now arrive as one
// aligned int4 per batch (rows 16B-aligned+padded).

#define ACC8(v)                                                         \
    s0 += bflo(v.x); s1 += bfhi(v.x); s2 += bflo(v.y); s3 += bfhi(v.y); \
    s4 += bflo(v.z); s5 += bfhi(v.z); s6 += bflo(v.w); s7 += bfhi(v.w);

__global__ __launch_bounds__(256) void fused_layer_k(
    const uint4* __restrict__ in4,    // bf16 rows [N][16 uint4]
    const int* __restrict__ rowptrA,  // padded 16B-aligned row starts
    const int* __restrict__ degA,     // degrees
    const int* __restrict__ csr,      // padded int neighbor ids
    const ushort* __restrict__ Wb,    // [128][256] bf16
    const float* __restrict__ bl,
    float* __restrict__ out,          // f32 out or null
    ushort* __restrict__ hb,          // bf16 out or null
    int N, int relu) {
    __shared__ uint4 At[32][16];

    int tid = threadIdx.x;
    int mt  = blockIdx.x;

    // ---- phase 1: aggregate (2 groups of 16 nodes) ----
    int lnode = tid >> 4;
    int c16   = tid & 15;
    #pragma unroll
    for (int g = 0; g < 2; ++g) {
        int lrow = g * 16 + lnode;
        int n = mt * 32 + lrow;
        float s0=0,s1=0,s2=0,s3=0,s4=0,s5=0,s6=0,s7=0;
        float inv = 0.f;
        if (n < N) {
            int ro  = rowptrA[n];
            int deg = degA[n];
            int i = 0;
            for (; i + 4 <= deg; i += 4) {
                int4 id = *(const int4*)(csr + ro + i);
                uint4 v0 = in4[(size_t)id.x * 16 + c16];
                uint4 v1 = in4[(size_t)id.y * 16 + c16];
                uint4 v2 = in4[(size_t)id.z * 16 + c16];
                uint4 v3 = in4[(size_t)id.w * 16 + c16];
                ACC8(v0); ACC8(v1); ACC8(v2); ACC8(v3);
            }
            if (i < deg) {
                int4 id = *(const int4*)(csr + ro + i);   // padded: safe read
                uint4 v0 = in4[(size_t)id.x * 16 + c16];
                ACC8(v0);
                if (i + 1 < deg) { uint4 v1 = in4[(size_t)id.y * 16 + c16]; ACC8(v1); }
                if (i + 2 < deg) { uint4 v2 = in4[(size_t)id.z * 16 + c16]; ACC8(v2); }
            }
            inv = (deg > 0) ? (1.f / (float)deg) : 0.f;
        }
        uint4 r;
        r.x = (bf16r(s1 * inv) << 16) | bf16r(s0 * inv);
        r.y = (bf16r(s3 * inv) << 16) | bf16r(s2 * inv);
        r.z = (bf16r(s5 * inv) << 16) | bf16r(s4 * inv);
        r.w = (bf16r(s7 * inv) << 16) | bf16r(s6 * inv);
        At[lrow][c16 ^ (lrow & 7)] = r;
    }
    __syncthreads();

    // ---- phase 2: MFMA ----
    int wid   = tid >> 6;
    int lane  = tid & 63;
    int col   = lane & 31;
    int khalf = lane >> 5;
    int nfeat = wid * 32 + col;

    bf16x8 B[16], A[16];
    const ushort* wrow = Wb + (size_t)nfeat * 256 + khalf * 8;
    #pragma unroll
    for (int ks = 0; ks < 16; ++ks)
        B[ks] = *reinterpret_cast<const bf16x8*>(wrow + ks * 16);

    #pragma unroll
    for (int ks = 0; ks < 8; ++ks) {
        int cc = (ks * 2 + khalf) ^ (col & 7);
        A[ks] = *reinterpret_cast<const bf16x8*>(&At[col][cc]);
    }
    int rowc = min(mt * 32 + col, N - 1);
    const ushort* ar1 = (const ushort*)in4 + (size_t)rowc * 128 + khalf * 8;
    #pragma unroll
    for (int ks = 0; ks < 8; ++ks)
        A[8 + ks] = *reinterpret_cast<const bf16x8*>(ar1 + ks * 16);

    f32x16 acc = {};
    #pragma unroll
    for (int ks = 0; ks < 16; ++ks)
        acc = __builtin_amdgcn_mfma_f32_32x32x16_bf16(A[ks], B[ks], acc, 0, 0, 0);

    float bias = bl[nfeat];
    #pragma unroll
    for (int r2 = 0; r2 < 16; ++r2) {
        int rr = (r2 & 3) + 8 * (r2 >> 2) + 4 * khalf;
        int gm = mt * 32 + rr;
        if (gm < N) {
            float v = acc[r2] + bias;
            if (relu) v = fmaxf(v, 0.f);
            if (out) __builtin_nontemporal_store(v, out + (size_t)gm * 128 + nfeat);
            if (hb)  hb[(size_t)gm * 128 + nfeat] = (ushort)bf16r(v);
        }
    }
}

extern "C" void kernel_launch(void* const* d_in, const int* in_sizes, int n_in,
                              void* d_out, int out_size, void* d_ws, size_t ws_size,
                              hipStream_t stream) {
    const float* x  = (const float*)d_in[0];
    const int*   ei = (const int*)d_in[1];
    const float* Wl = (const float*)d_in[2];
    const float* bl = (const float*)d_in[3];
    const float* Wr = (const float*)d_in[4];
    float* out = (float*)d_out;

    const int N = NN;
    const int E = in_sizes[1] / 2;
    const int NPAD = 50016;

    int nebl = (E + BLK_E - 1) / BLK_E;       // 157
    int nprt = (N + 255) / 256;               // 196 partitions

    // ws layout (u32 units):
    // rowptrA[N] | degA[N] | counts[nebl*256] | binBase[260] | upack[E]
    // | csr[E + nprt*768 + 64] | wb[16384] | xb[NPAD*64] | hb[NPAD*64]
    int*  ws      = (int*)d_ws;
    int*  rowptrA = ws;
    int*  degA    = ws + N;
    int*  counts  = ws + 2 * N;
    int*  binBase = counts + nebl * 256;
    uint* upack   = (uint*)(binBase + 260);
    int*  csr     = (int*)(upack + E);
    int   csrSz   = E + nprt * 768 + 64;
    uint* wb      = (uint*)(csr + csrSz);
    uint* xb      = wb + 128 * 128;
    uint* hb      = xb + (size_t)NPAD * 64;

    int nquad = N * 32;
    int cvtb  = (nquad + 255) / 256;

    passA_k<<<nebl + 64 + cvtb, 256, 0, stream>>>(ei, E, counts, nebl,
                                                  Wl, Wr, wb, x, xb, nquad);
    passB_k<<<1, 256, 0, stream>>>(counts, nebl, binBase);
    passC_k<<<nebl, 256, 0, stream>>>(ei, E, counts, binBase, upack, nebl);
    passD_k<<<nprt, 256, 0, stream>>>(upack, binBase, rowptrA, degA, csr, N);

    int mtiles = (N + 31) / 32;        // 1563
    // layer 1: gather from xb, output bf16 hb only
    fused_layer_k<<<mtiles, 256, 0, stream>>>((const uint4*)xb, rowptrA, degA, csr,
                                              (const ushort*)wb, bl,
                                              (float*)nullptr, (ushort*)hb, N, 1);
    // layer 2: gather from hb, output f32 out (nontemporal)
    fused_layer_k<<<mtiles, 256, 0, stream>>>((const uint4*)hb, rowptrA, degA, csr,
                                              (const ushort*)wb, bl,
                                              out, (ushort*)nullptr, N, 0);
}